// Round 2
// baseline (970.994 us; speedup 1.0000x reference)
//
#include <hip/hip_runtime.h>
#include <cstdint>

#define F_IN 500
#define HID  64
#define NCLS 7

static inline size_t align_up(size_t v, size_t a) { return (v + a - 1) & ~(a - 1); }

// deg[d] += 1 for each edge target
__global__ void deg_kernel(const int* __restrict__ dst, float* __restrict__ deg, int E) {
    int i = blockIdx.x * blockDim.x + threadIdx.x;
    if (i < E) unsafeAtomicAdd(&deg[dst[i]], 1.0f);
}

// deg -> dinv = rsqrt(deg + 1)   (+1 = self loop; always > 0)
__global__ void dinv_kernel(float* __restrict__ deg, int n) {
    int i = blockIdx.x * blockDim.x + threadIdx.x;
    if (i < n) deg[i] = rsqrtf(deg[i] + 1.0f);
}

// h0 = x @ W1 ; h1 = h0 * dinv^2 (self-loop init of layer-1 aggregation)
// block = 256 threads (4 waves), 8 rows/wave -> 32 rows/block.
// W1 staged in LDS in 128-row K-chunks (32 KB). lane = output column (HID=64).
__global__ __launch_bounds__(256) void gemm1_kernel(
    const float* __restrict__ x, const float* __restrict__ W1,
    const float* __restrict__ dinv,
    float* __restrict__ h0, float* __restrict__ h1, int n)
{
    __shared__ float Ws[128][HID];
    const int lane = threadIdx.x & 63;
    const int wave = threadIdx.x >> 6;
    const int row0 = blockIdx.x * 32 + wave * 8;

    float acc[8] = {0.f, 0.f, 0.f, 0.f, 0.f, 0.f, 0.f, 0.f};

    for (int kc = 0; kc < 4; ++kc) {
        const int kbase  = kc * 128;
        const int kcount = (kc == 3) ? 116 : 128;   // 500 = 3*128 + 116 (both %4==0)
        __syncthreads();
        for (int f = threadIdx.x; f < kcount * (HID / 4); f += 256) {
            int k  = f >> 4;
            int c4 = f & 15;
            float4 v = *reinterpret_cast<const float4*>(W1 + (size_t)(kbase + k) * HID + c4 * 4);
            *reinterpret_cast<float4*>(&Ws[k][c4 * 4]) = v;
        }
        __syncthreads();
        const int nk4 = kcount >> 2;
        for (int k4 = 0; k4 < nk4; ++k4) {
            const float w0 = Ws[k4 * 4 + 0][lane];
            const float w1 = Ws[k4 * 4 + 1][lane];
            const float w2 = Ws[k4 * 4 + 2][lane];
            const float w3 = Ws[k4 * 4 + 3][lane];
            #pragma unroll
            for (int r = 0; r < 8; ++r) {
                int row = row0 + r;
                row = (row < n) ? row : (n - 1);   // clamp; stores are guarded
                float4 xv = *reinterpret_cast<const float4*>(
                    x + (size_t)row * F_IN + kbase + k4 * 4);
                float a = acc[r];
                a = fmaf(xv.x, w0, a);
                a = fmaf(xv.y, w1, a);
                a = fmaf(xv.z, w2, a);
                a = fmaf(xv.w, w3, a);
                acc[r] = a;
            }
        }
    }
    const int lane2 = threadIdx.x & 63;
    #pragma unroll
    for (int r = 0; r < 8; ++r) {
        int row = row0 + r;
        if (row < n) {
            float v = acc[r];
            h0[(size_t)row * HID + lane2] = v;
            float di = dinv[row];
            h1[(size_t)row * HID + lane2] = v * di * di;
        }
    }
}

// h1[dst] += h0[src] * dinv[src]*dinv[dst]  — one wave per edge, lane = channel
__global__ void agg1_kernel(const int* __restrict__ src, const int* __restrict__ dst,
                            const float* __restrict__ dinv, const float* __restrict__ h0,
                            float* __restrict__ h1, int total)
{
    int idx = blockIdx.x * blockDim.x + threadIdx.x;
    if (idx >= total) return;
    int e = idx >> 6;
    int c = idx & 63;
    int s = src[e];
    int d = dst[e];
    float w = dinv[s] * dinv[d];
    unsafeAtomicAdd(&h1[(size_t)d * HID + c], h0[(size_t)s * HID + c] * w);
}

// h2 = relu(h1 + b1) @ W2 ; out = h2 * dinv^2 + b2  (self-loop init + bias of layer 2)
// thread = (row, c) with c in 0..7 (c==7 idle on store)
__global__ __launch_bounds__(256) void gemm2_kernel(
    const float* __restrict__ h1, const float* __restrict__ b1,
    const float* __restrict__ W2, const float* __restrict__ b2,
    const float* __restrict__ dinv,
    float* __restrict__ h2, float* __restrict__ out, int n)
{
    __shared__ float W2s[HID][8];
    __shared__ float b1s[HID];
    __shared__ float b2s[8];
    for (int i = threadIdx.x; i < HID * 8; i += 256) {
        int k = i >> 3, c = i & 7;
        W2s[k][c] = (c < NCLS) ? W2[k * NCLS + c] : 0.0f;
    }
    if (threadIdx.x < HID) b1s[threadIdx.x] = b1[threadIdx.x];
    if (threadIdx.x < 8)   b2s[threadIdx.x] = (threadIdx.x < NCLS) ? b2[threadIdx.x] : 0.0f;
    __syncthreads();

    int idx = blockIdx.x * 256 + threadIdx.x;
    int row = idx >> 3;
    int c   = idx & 7;
    if (row >= n) return;

    float acc = 0.f;
    const float* hr = h1 + (size_t)row * HID;
    #pragma unroll
    for (int k4 = 0; k4 < HID / 4; ++k4) {
        float4 hv = *reinterpret_cast<const float4*>(hr + k4 * 4);
        float v0 = fmaxf(hv.x + b1s[k4 * 4 + 0], 0.f);
        float v1 = fmaxf(hv.y + b1s[k4 * 4 + 1], 0.f);
        float v2 = fmaxf(hv.z + b1s[k4 * 4 + 2], 0.f);
        float v3 = fmaxf(hv.w + b1s[k4 * 4 + 3], 0.f);
        acc = fmaf(v0, W2s[k4 * 4 + 0][c], acc);
        acc = fmaf(v1, W2s[k4 * 4 + 1][c], acc);
        acc = fmaf(v2, W2s[k4 * 4 + 2][c], acc);
        acc = fmaf(v3, W2s[k4 * 4 + 3][c], acc);
    }
    if (c < NCLS) {
        h2[(size_t)row * NCLS + c] = acc;
        float di = dinv[row];
        out[(size_t)row * NCLS + c] = fmaf(acc, di * di, b2s[c]);
    }
}

// out[dst] += h2[src] * dinv[src]*dinv[dst]  — 8 threads per edge (c==7 idle)
__global__ void agg2_kernel(const int* __restrict__ src, const int* __restrict__ dst,
                            const float* __restrict__ dinv, const float* __restrict__ h2,
                            float* __restrict__ out, int total)
{
    int idx = blockIdx.x * blockDim.x + threadIdx.x;
    if (idx >= total) return;
    int e = idx >> 3;
    int c = idx & 7;
    if (c >= NCLS) return;
    int s = src[e];
    int d = dst[e];
    float w = dinv[s] * dinv[d];
    unsafeAtomicAdd(&out[(size_t)d * NCLS + c], h2[(size_t)s * NCLS + c] * w);
}

extern "C" void kernel_launch(void* const* d_in, const int* in_sizes, int n_in,
                              void* d_out, int out_size, void* d_ws, size_t ws_size,
                              hipStream_t stream)
{
    const float* x  = (const float*)d_in[0];
    const float* W1 = (const float*)d_in[1];
    const float* b1 = (const float*)d_in[2];
    const float* W2 = (const float*)d_in[3];
    const float* b2 = (const float*)d_in[4];
    const int*   ei = (const int*)d_in[5];

    const int n = in_sizes[0] / F_IN;
    const int E = in_sizes[5] / 2;
    const int* src = ei;
    const int* dst = ei + E;

    char* ws = (char*)d_ws;
    size_t off = 0;
    float* dinv = (float*)(ws + off); off += align_up((size_t)n * 4, 256);
    float* h0   = (float*)(ws + off); off += align_up((size_t)n * HID * 4, 256);
    float* h1   = (float*)(ws + off); off += align_up((size_t)n * HID * 4, 256);
    float* h2   = (float*)(ws + off); off += align_up((size_t)n * NCLS * 4, 256);
    float* out  = (float*)d_out;

    // degree buffer must start at 0 (ws is poisoned 0xAA each call)
    hipMemsetAsync(dinv, 0, (size_t)n * 4, stream);
    deg_kernel<<<(E + 255) / 256, 256, 0, stream>>>(dst, dinv, E);
    dinv_kernel<<<(n + 255) / 256, 256, 0, stream>>>(dinv, n);

    gemm1_kernel<<<(n + 31) / 32, 256, 0, stream>>>(x, W1, dinv, h0, h1, n);

    const int tot1 = E * HID;
    agg1_kernel<<<(tot1 + 255) / 256, 256, 0, stream>>>(src, dst, dinv, h0, h1, tot1);

    gemm2_kernel<<<(n + 31) / 32, 256, 0, stream>>>(h1, b1, W2, b2, dinv, h2, out, n);

    const int tot2 = E * 8;
    agg2_kernel<<<(tot2 + 255) / 256, 256, 0, stream>>>(src, dst, dinv, h2, out, tot2);
}

// Round 4
// 563.301 us; speedup vs baseline: 1.7238x; 1.7238x over previous
//
#include <hip/hip_runtime.h>
#include <cstdint>

#define F_IN 500
#define HID  64
#define NCLS 7
#define KCH  100            // K-chunk for gemm1 (500 = 5*100)
#define XS_STRIDE 108       // 64-row X tile, padded stride (4-row step -> bank +16, 2-way = free)

static inline size_t align_up(size_t v, size_t a) { return (v + a - 1) & ~(a - 1); }

// ---------- degree histogram (int) ----------
__global__ void hist_kernel(const int* __restrict__ dst, int* __restrict__ hist, int E) {
    int i = blockIdx.x * blockDim.x + threadIdx.x;
    if (i < E) atomicAdd(&hist[dst[i]], 1);
}

// ---------- dinv = rsqrt(deg+1) ----------
__global__ void dinv_kernel(const int* __restrict__ hist, float* __restrict__ dinv, int n) {
    int i = blockIdx.x * blockDim.x + threadIdx.x;
    if (i < n) dinv[i] = rsqrtf((float)hist[i] + 1.0f);
}

// ---------- two-level exclusive scan of hist -> rowstart ----------
__global__ __launch_bounds__(256) void scan1_kernel(const int* __restrict__ hist,
                                                    int* __restrict__ rowstart,
                                                    int* __restrict__ bsum, int n) {
    __shared__ int sdat[256];
    int tid = threadIdx.x;
    int i = blockIdx.x * 256 + tid;
    int v = (i < n) ? hist[i] : 0;
    sdat[tid] = v;
    __syncthreads();
    for (int off = 1; off < 256; off <<= 1) {
        int t = (tid >= off) ? sdat[tid - off] : 0;
        __syncthreads();
        sdat[tid] += t;
        __syncthreads();
    }
    int incl = sdat[tid];
    if (i < n) rowstart[i] = incl - v;           // in-block exclusive
    if (tid == 255) bsum[blockIdx.x] = incl;     // block total
}

__global__ __launch_bounds__(512) void scan2_kernel(int* __restrict__ bsum, int nb) {
    __shared__ int sdat[512];
    int tid = threadIdx.x;
    int v = (tid < nb) ? bsum[tid] : 0;
    sdat[tid] = v;
    __syncthreads();
    for (int off = 1; off < 512; off <<= 1) {
        int t = (tid >= off) ? sdat[tid - off] : 0;
        __syncthreads();
        sdat[tid] += t;
        __syncthreads();
    }
    bsum[tid] = sdat[tid] - v;                   // exclusive block offsets
}

__global__ void scan3_kernel(int* __restrict__ rowstart, const int* __restrict__ bsum,
                             int* __restrict__ cursor, int n, int E) {
    int i = blockIdx.x * blockDim.x + threadIdx.x;
    if (i < n) {
        int val = rowstart[i] + bsum[i >> 8];
        rowstart[i] = val;
        cursor[i] = val;
    }
    if (i == 0) rowstart[n] = E;
}

// ---------- scatter edges into CSR (grouped by dst) ----------
__global__ void scatter_kernel(const int* __restrict__ src, const int* __restrict__ dst,
                               int* __restrict__ cursor, int* __restrict__ csrc, int E) {
    int e = blockIdx.x * blockDim.x + threadIdx.x;
    if (e < E) {
        int d = dst[e];
        int pos = atomicAdd(&cursor[d], 1);
        csrc[pos] = src[e];
    }
}

// ---------- GEMM1: h0 = x @ W1, tiled (64 rows x 64 cols), LDS-staged ----------
__global__ __launch_bounds__(256) void gemm1_kernel(
    const float* __restrict__ x, const float* __restrict__ W1,
    float* __restrict__ h0, int n)
{
    __shared__ float Xs[64 * XS_STRIDE];   // 64 x 100 (padded to 108)
    __shared__ float Ws[KCH * HID];        // 100 x 64

    const int tid  = threadIdx.x;
    const int col4 = (tid & 15) * 4;       // 4 output cols
    const int row4 = (tid >> 4) * 4;       // 4 output rows within tile
    const int row0 = blockIdx.x * 64;

    float acc[4][4];
    #pragma unroll
    for (int r = 0; r < 4; ++r)
        #pragma unroll
        for (int c = 0; c < 4; ++c) acc[r][c] = 0.f;

    for (int kc = 0; kc < 5; ++kc) {
        const int kbase = kc * KCH;
        __syncthreads();
        // stage X tile: 64 rows x 25 float4
        for (int f = tid; f < 64 * 25; f += 256) {
            int r  = f / 25;
            int c4 = f - r * 25;
            int row = row0 + r;
            row = (row < n) ? row : (n - 1);
            float4 v = *reinterpret_cast<const float4*>(x + (size_t)row * F_IN + kbase + c4 * 4);
            *reinterpret_cast<float4*>(&Xs[r * XS_STRIDE + c4 * 4]) = v;
        }
        // stage W chunk: 100 x 16 float4
        for (int f = tid; f < KCH * 16; f += 256) {
            int k  = f >> 4;
            int c4 = f & 15;
            float4 v = *reinterpret_cast<const float4*>(W1 + (size_t)(kbase + k) * HID + c4 * 4);
            *reinterpret_cast<float4*>(&Ws[k * HID + c4 * 4]) = v;
        }
        __syncthreads();

        for (int k4 = 0; k4 < KCH / 4; ++k4) {
            float4 Xv[4], Wv[4];
            #pragma unroll
            for (int r = 0; r < 4; ++r)
                Xv[r] = *reinterpret_cast<const float4*>(&Xs[(row4 + r) * XS_STRIDE + k4 * 4]);
            #pragma unroll
            for (int j = 0; j < 4; ++j)
                Wv[j] = *reinterpret_cast<const float4*>(&Ws[(k4 * 4 + j) * HID + col4]);
            #pragma unroll
            for (int r = 0; r < 4; ++r) {
                acc[r][0] = fmaf(Xv[r].x, Wv[0].x, acc[r][0]);
                acc[r][1] = fmaf(Xv[r].x, Wv[0].y, acc[r][1]);
                acc[r][2] = fmaf(Xv[r].x, Wv[0].z, acc[r][2]);
                acc[r][3] = fmaf(Xv[r].x, Wv[0].w, acc[r][3]);
                acc[r][0] = fmaf(Xv[r].y, Wv[1].x, acc[r][0]);
                acc[r][1] = fmaf(Xv[r].y, Wv[1].y, acc[r][1]);
                acc[r][2] = fmaf(Xv[r].y, Wv[1].z, acc[r][2]);
                acc[r][3] = fmaf(Xv[r].y, Wv[1].w, acc[r][3]);
                acc[r][0] = fmaf(Xv[r].z, Wv[2].x, acc[r][0]);
                acc[r][1] = fmaf(Xv[r].z, Wv[2].y, acc[r][1]);
                acc[r][2] = fmaf(Xv[r].z, Wv[2].z, acc[r][2]);
                acc[r][3] = fmaf(Xv[r].z, Wv[2].w, acc[r][3]);
                acc[r][0] = fmaf(Xv[r].w, Wv[3].x, acc[r][0]);
                acc[r][1] = fmaf(Xv[r].w, Wv[3].y, acc[r][1]);
                acc[r][2] = fmaf(Xv[r].w, Wv[3].z, acc[r][2]);
                acc[r][3] = fmaf(Xv[r].w, Wv[3].w, acc[r][3]);
            }
        }
    }

    #pragma unroll
    for (int r = 0; r < 4; ++r) {
        int row = row0 + row4 + r;
        if (row < n) {
            float4 v = make_float4(acc[r][0], acc[r][1], acc[r][2], acc[r][3]);
            *reinterpret_cast<float4*>(h0 + (size_t)row * HID + col4) = v;
        }
    }
}

// ---------- fused layer-1 aggregation + GEMM2: wave per node ----------
// h1[d][c] = dinv[d] * (sum_{s in N(d)} dinv[s]*h0[s][c] + dinv[d]*h0[d][c])
// h2[d][c'] = sum_c relu(h1[d][c] + b1[c]) * W2[c][c']   (c' in 0..6, stored padded to 8)
__global__ __launch_bounds__(256) void agg1_gemm2_kernel(
    const float* __restrict__ h0, const float* __restrict__ dinv,
    const int* __restrict__ rowstart, const int* __restrict__ csrc,
    const float* __restrict__ b1, const float* __restrict__ W2,
    float* __restrict__ h2, int n)
{
    __shared__ float W2s[HID][9];   // pad 9: lane*9 coprime with 32 -> 2-way max
    __shared__ float b1s[HID];
    for (int i = threadIdx.x; i < HID * 8; i += 256) {
        int k = i >> 3, c = i & 7;
        W2s[k][c] = (c < NCLS) ? W2[k * NCLS + c] : 0.f;
    }
    if (threadIdx.x < HID) b1s[threadIdx.x] = b1[threadIdx.x];
    __syncthreads();

    const int lane = threadIdx.x & 63;
    const int wave = threadIdx.x >> 6;
    const int d = blockIdx.x * 4 + wave;
    if (d >= n) return;

    const int js = rowstart[d];
    const int je = rowstart[d + 1];
    float acc = 0.f;
    for (int j = js; j < je; ++j) {
        int s = csrc[j];
        acc = fmaf(h0[(size_t)s * HID + lane], dinv[s], acc);
    }
    const float dd = dinv[d];
    float v = (acc + dd * h0[(size_t)d * HID + lane]) * dd;
    float p = fmaxf(v + b1s[lane], 0.f);

    float t0 = p * W2s[lane][0];
    float t1 = p * W2s[lane][1];
    float t2 = p * W2s[lane][2];
    float t3 = p * W2s[lane][3];
    float t4 = p * W2s[lane][4];
    float t5 = p * W2s[lane][5];
    float t6 = p * W2s[lane][6];
    #pragma unroll
    for (int off = 32; off > 0; off >>= 1) {
        t0 += __shfl_xor(t0, off);
        t1 += __shfl_xor(t1, off);
        t2 += __shfl_xor(t2, off);
        t3 += __shfl_xor(t3, off);
        t4 += __shfl_xor(t4, off);
        t5 += __shfl_xor(t5, off);
        t6 += __shfl_xor(t6, off);
    }
    float sel = t0;
    sel = (lane == 1) ? t1 : sel;
    sel = (lane == 2) ? t2 : sel;
    sel = (lane == 3) ? t3 : sel;
    sel = (lane == 4) ? t4 : sel;
    sel = (lane == 5) ? t5 : sel;
    sel = (lane == 6) ? t6 : sel;
    if (lane < NCLS) h2[(size_t)d * 8 + lane] = sel;
}

// ---------- layer-2 aggregation: 8 lanes per node, gather over CSR ----------
__global__ void agg2_kernel(const float* __restrict__ h2, const float* __restrict__ dinv,
                            const int* __restrict__ rowstart, const int* __restrict__ csrc,
                            const float* __restrict__ b2, float* __restrict__ out, int n)
{
    int idx = blockIdx.x * blockDim.x + threadIdx.x;
    int d = idx >> 3;
    int c = idx & 7;
    if (d >= n) return;

    const int js = rowstart[d];
    const int je = rowstart[d + 1];
    float acc = 0.f;
    for (int j = js; j < je; ++j) {
        int s = csrc[j];
        acc = fmaf(h2[(size_t)s * 8 + c], dinv[s], acc);
    }
    const float dd = dinv[d];
    if (c < NCLS)
        out[(size_t)d * NCLS + c] = fmaf(acc + dd * h2[(size_t)d * 8 + c], dd, b2[c]);
}

extern "C" void kernel_launch(void* const* d_in, const int* in_sizes, int n_in,
                              void* d_out, int out_size, void* d_ws, size_t ws_size,
                              hipStream_t stream)
{
    const float* x  = (const float*)d_in[0];
    const float* W1 = (const float*)d_in[1];
    const float* b1 = (const float*)d_in[2];
    const float* W2 = (const float*)d_in[3];
    const float* b2 = (const float*)d_in[4];
    const int*   ei = (const int*)d_in[5];

    const int n = in_sizes[0] / F_IN;
    const int E = in_sizes[5] / 2;
    const int* src = ei;
    const int* dst = ei + E;

    char* ws = (char*)d_ws;
    size_t off = 0;
    int*   hist     = (int*)(ws + off);   off += align_up((size_t)n * 4, 256);        // also reused as cursor
    int*   rowstart = (int*)(ws + off);   off += align_up((size_t)(n + 1) * 4, 256);
    int*   bsum     = (int*)(ws + off);   off += align_up((size_t)512 * 4, 256);
    int*   csrc     = (int*)(ws + off);   off += align_up((size_t)E * 4, 256);
    float* dinv     = (float*)(ws + off); off += align_up((size_t)n * 4, 256);
    float* h0       = (float*)(ws + off); off += align_up((size_t)n * HID * 4, 256);
    float* h2       = (float*)(ws + off); off += align_up((size_t)n * 8 * 4, 256);
    float* out      = (float*)d_out;

    const int nb = (n + 255) / 256;   // 349 scan blocks (< 512)

    hipMemsetAsync(hist, 0, (size_t)n * 4, stream);
    hist_kernel<<<(E + 255) / 256, 256, 0, stream>>>(dst, hist, E);
    dinv_kernel<<<nb, 256, 0, stream>>>(hist, dinv, n);
    scan1_kernel<<<nb, 256, 0, stream>>>(hist, rowstart, bsum, n);
    scan2_kernel<<<1, 512, 0, stream>>>(bsum, nb);
    scan3_kernel<<<nb, 256, 0, stream>>>(rowstart, bsum, hist /*cursor*/, n, E);
    scatter_kernel<<<(E + 255) / 256, 256, 0, stream>>>(src, dst, hist /*cursor*/, csrc, E);

    gemm1_kernel<<<(n + 63) / 64, 256, 0, stream>>>(x, W1, h0, n);

    agg1_gemm2_kernel<<<(n + 3) / 4, 256, 0, stream>>>(h0, dinv, rowstart, csrc, b1, W2, h2, n);

    agg2_kernel<<<((size_t)n * 8 + 255) / 256, 256, 0, stream>>>(h2, dinv, rowstart, csrc, b2, out, n);
}

// Round 5
// 503.902 us; speedup vs baseline: 1.9270x; 1.1179x over previous
//
#include <hip/hip_runtime.h>
#include <cstdint>

#define F_IN 500
#define HID  64
#define NCLS 7

typedef __attribute__((ext_vector_type(8))) short v8s;
typedef __attribute__((ext_vector_type(4))) short v4s;
typedef __attribute__((ext_vector_type(4))) float v4f;

union S8 { v8s v; v4s h[2]; };

static inline size_t align_up(size_t v, size_t a) { return (v + a - 1) & ~(a - 1); }

__device__ inline unsigned short f2bf(float f) {
    unsigned int u = __float_as_uint(f);
    u += 0x7FFF + ((u >> 16) & 1);       // round-to-nearest-even
    return (unsigned short)(u >> 16);
}

// ---------- degree histogram (int) ----------
__global__ void hist_kernel(const int* __restrict__ dst, int* __restrict__ hist, int E) {
    int i = blockIdx.x * blockDim.x + threadIdx.x;
    if (i < E) atomicAdd(&hist[dst[i]], 1);
}

// ---------- dinv = rsqrt(deg+1) ----------
__global__ void dinv_kernel(const int* __restrict__ hist, float* __restrict__ dinv, int n) {
    int i = blockIdx.x * blockDim.x + threadIdx.x;
    if (i < n) dinv[i] = rsqrtf((float)hist[i] + 1.0f);
}

// ---------- two-level exclusive scan of hist -> rowstart ----------
__global__ __launch_bounds__(256) void scan1_kernel(const int* __restrict__ hist,
                                                    int* __restrict__ rowstart,
                                                    int* __restrict__ bsum, int n) {
    __shared__ int sdat[256];
    int tid = threadIdx.x;
    int i = blockIdx.x * 256 + tid;
    int v = (i < n) ? hist[i] : 0;
    sdat[tid] = v;
    __syncthreads();
    for (int off = 1; off < 256; off <<= 1) {
        int t = (tid >= off) ? sdat[tid - off] : 0;
        __syncthreads();
        sdat[tid] += t;
        __syncthreads();
    }
    int incl = sdat[tid];
    if (i < n) rowstart[i] = incl - v;           // in-block exclusive
    if (tid == 255) bsum[blockIdx.x] = incl;     // block total
}

__global__ __launch_bounds__(512) void scan2_kernel(int* __restrict__ bsum, int nb) {
    __shared__ int sdat[512];
    int tid = threadIdx.x;
    int v = (tid < nb) ? bsum[tid] : 0;
    sdat[tid] = v;
    __syncthreads();
    for (int off = 1; off < 512; off <<= 1) {
        int t = (tid >= off) ? sdat[tid - off] : 0;
        __syncthreads();
        sdat[tid] += t;
        __syncthreads();
    }
    bsum[tid] = sdat[tid] - v;                   // exclusive block offsets
}

__global__ void scan3_kernel(int* __restrict__ rowstart, const int* __restrict__ bsum,
                             int* __restrict__ cursor, int n, int E) {
    int i = blockIdx.x * blockDim.x + threadIdx.x;
    if (i < n) {
        int val = rowstart[i] + bsum[i >> 8];
        rowstart[i] = val;
        cursor[i] = val;
    }
    if (i == 0) rowstart[n] = E;
}

// ---------- scatter edges into CSR (grouped by dst) ----------
__global__ void scatter_kernel(const int* __restrict__ src, const int* __restrict__ dst,
                               int* __restrict__ cursor, int* __restrict__ csrc, int E) {
    int e = blockIdx.x * blockDim.x + threadIdx.x;
    if (e < E) {
        int d = dst[e];
        int pos = atomicAdd(&cursor[d], 1);
        csrc[pos] = src[e];
    }
}

// ---------- W1 -> bf16 transposed+padded  Wt[64][512] ----------
__global__ void wt_kernel(const float* __restrict__ W1, unsigned short* __restrict__ Wt) {
    int id = blockIdx.x * 256 + threadIdx.x;   // 64*512
    if (id >= HID * 512) return;
    int c = id >> 9;
    int k = id & 511;
    Wt[(size_t)c * 512 + k] = (k < F_IN) ? f2bf(W1[(size_t)k * HID + c]) : (unsigned short)0;
}

// ---------- GEMM1 via bf16 MFMA: h0(fp32) = x @ W1 ----------
// tile 128 rows x 64 cols, block 256 thr (4 waves), wave = 32 rows x 64 cols
// = 2x4 tiles of 16x16, K-step 32 (16 steps, last zero-padded 20).
// LDS strides padded to 36 shorts (72B = 18 banks -> <=2-way, free).
__global__ __launch_bounds__(256) void gemm1_mfma_kernel(
    const float* __restrict__ x, const unsigned short* __restrict__ Wt,
    float* __restrict__ h0, int n)
{
    __shared__ unsigned short Al[128][36];
    __shared__ unsigned short Bl[64][36];

    const int tid  = threadIdx.x;
    const int lane = tid & 63;
    const int wave = tid >> 6;
    const int row0 = blockIdx.x * 128;
    const int l15  = lane & 15;
    const int kq   = (lane >> 4) * 4;

    v4f acc[2][4];
    #pragma unroll
    for (int rb = 0; rb < 2; ++rb)
        #pragma unroll
        for (int cb = 0; cb < 4; ++cb) acc[rb][cb] = (v4f)(0.0f);

    const int a_c4 = tid & 7;     // float4 index along k within chunk
    const int a_r  = tid >> 3;    // row 0..31 (+32*i)
    const int b_c  = tid >> 2;    // col 0..63
    const int b_k8 = (tid & 3) * 8;

    for (int ks = 0; ks < 16; ++ks) {
        const int kbase = ks * 32;
        __syncthreads();
        // stage A: x[row0..row0+128][kbase..kbase+32] fp32 -> bf16
        #pragma unroll
        for (int i = 0; i < 4; ++i) {
            const int r = a_r + 32 * i;
            int row = row0 + r;
            row = (row < n) ? row : (n - 1);
            v4s o;
            if (kbase + a_c4 * 4 < F_IN) {
                float4 v = *reinterpret_cast<const float4*>(
                    x + (size_t)row * F_IN + kbase + a_c4 * 4);
                o.x = (short)f2bf(v.x); o.y = (short)f2bf(v.y);
                o.z = (short)f2bf(v.z); o.w = (short)f2bf(v.w);
            } else {
                o = (v4s)(short)0;
            }
            *reinterpret_cast<v4s*>(&Al[r][a_c4 * 4]) = o;
        }
        // stage B: Wt[col][kbase..kbase+32] (already bf16, zero-padded)
        {
            const unsigned short* p = Wt + (size_t)b_c * 512 + kbase + b_k8;
            v4s lo = *reinterpret_cast<const v4s*>(p);
            v4s hi = *reinterpret_cast<const v4s*>(p + 4);
            *reinterpret_cast<v4s*>(&Bl[b_c][b_k8])     = lo;
            *reinterpret_cast<v4s*>(&Bl[b_c][b_k8 + 4]) = hi;
        }
        __syncthreads();

        // fragments + MFMA
        S8 af[2], bq[4];
        #pragma unroll
        for (int rb = 0; rb < 2; ++rb) {
            const int row = wave * 32 + rb * 16 + l15;
            af[rb].h[0] = *reinterpret_cast<const v4s*>(&Al[row][kq]);
            af[rb].h[1] = *reinterpret_cast<const v4s*>(&Al[row][kq + 16]);
        }
        #pragma unroll
        for (int cb = 0; cb < 4; ++cb) {
            const int col = cb * 16 + l15;
            bq[cb].h[0] = *reinterpret_cast<const v4s*>(&Bl[col][kq]);
            bq[cb].h[1] = *reinterpret_cast<const v4s*>(&Bl[col][kq + 16]);
        }
        #pragma unroll
        for (int rb = 0; rb < 2; ++rb)
            #pragma unroll
            for (int cb = 0; cb < 4; ++cb)
                acc[rb][cb] = __builtin_amdgcn_mfma_f32_16x16x32_bf16(
                    af[rb].v, bq[cb].v, acc[rb][cb], 0, 0, 0);
    }

    // store C: col = cb*16 + (lane&15), row = (lane>>4)*4 + j  [m89-verified]
    #pragma unroll
    for (int rb = 0; rb < 2; ++rb) {
        #pragma unroll
        for (int cb = 0; cb < 4; ++cb) {
            #pragma unroll
            for (int j = 0; j < 4; ++j) {
                int row = row0 + wave * 32 + rb * 16 + (lane >> 4) * 4 + j;
                if (row < n)
                    h0[(size_t)row * HID + cb * 16 + l15] = acc[rb][cb][j];
            }
        }
    }
}

// ---------- fused layer-1 aggregation + GEMM2: wave per node ----------
__global__ __launch_bounds__(256) void agg1_gemm2_kernel(
    const float* __restrict__ h0, const float* __restrict__ dinv,
    const int* __restrict__ rowstart, const int* __restrict__ csrc,
    const float* __restrict__ b1, const float* __restrict__ W2,
    float* __restrict__ h2, int n)
{
    __shared__ float W2s[HID][9];
    __shared__ float b1s[HID];
    for (int i = threadIdx.x; i < HID * 8; i += 256) {
        int k = i >> 3, c = i & 7;
        W2s[k][c] = (c < NCLS) ? W2[k * NCLS + c] : 0.f;
    }
    if (threadIdx.x < HID) b1s[threadIdx.x] = b1[threadIdx.x];
    __syncthreads();

    const int lane = threadIdx.x & 63;
    const int wave = threadIdx.x >> 6;
    const int d = blockIdx.x * 4 + wave;
    if (d >= n) return;

    const int js = rowstart[d];
    const int je = rowstart[d + 1];
    float acc = 0.f;
    for (int j = js; j < je; ++j) {
        int s = csrc[j];
        acc = fmaf(h0[(size_t)s * HID + lane], dinv[s], acc);
    }
    const float dd = dinv[d];
    float v = (acc + dd * h0[(size_t)d * HID + lane]) * dd;
    float p = fmaxf(v + b1s[lane], 0.f);

    float t0 = p * W2s[lane][0];
    float t1 = p * W2s[lane][1];
    float t2 = p * W2s[lane][2];
    float t3 = p * W2s[lane][3];
    float t4 = p * W2s[lane][4];
    float t5 = p * W2s[lane][5];
    float t6 = p * W2s[lane][6];
    #pragma unroll
    for (int off = 32; off > 0; off >>= 1) {
        t0 += __shfl_xor(t0, off);
        t1 += __shfl_xor(t1, off);
        t2 += __shfl_xor(t2, off);
        t3 += __shfl_xor(t3, off);
        t4 += __shfl_xor(t4, off);
        t5 += __shfl_xor(t5, off);
        t6 += __shfl_xor(t6, off);
    }
    float sel = t0;
    sel = (lane == 1) ? t1 : sel;
    sel = (lane == 2) ? t2 : sel;
    sel = (lane == 3) ? t3 : sel;
    sel = (lane == 4) ? t4 : sel;
    sel = (lane == 5) ? t5 : sel;
    sel = (lane == 6) ? t6 : sel;
    if (lane < NCLS) h2[(size_t)d * 8 + lane] = sel;
}

// ---------- layer-2 aggregation: 8 lanes per node, gather over CSR ----------
__global__ void agg2_kernel(const float* __restrict__ h2, const float* __restrict__ dinv,
                            const int* __restrict__ rowstart, const int* __restrict__ csrc,
                            const float* __restrict__ b2, float* __restrict__ out, int n)
{
    int idx = blockIdx.x * blockDim.x + threadIdx.x;
    int d = idx >> 3;
    int c = idx & 7;
    if (d >= n) return;

    const int js = rowstart[d];
    const int je = rowstart[d + 1];
    float acc = 0.f;
    for (int j = js; j < je; ++j) {
        int s = csrc[j];
        acc = fmaf(h2[(size_t)s * 8 + c], dinv[s], acc);
    }
    const float dd = dinv[d];
    if (c < NCLS)
        out[(size_t)d * NCLS + c] = fmaf(acc + dd * h2[(size_t)d * 8 + c], dd, b2[c]);
}

extern "C" void kernel_launch(void* const* d_in, const int* in_sizes, int n_in,
                              void* d_out, int out_size, void* d_ws, size_t ws_size,
                              hipStream_t stream)
{
    const float* x  = (const float*)d_in[0];
    const float* W1 = (const float*)d_in[1];
    const float* b1 = (const float*)d_in[2];
    const float* W2 = (const float*)d_in[3];
    const float* b2 = (const float*)d_in[4];
    const int*   ei = (const int*)d_in[5];

    const int n = in_sizes[0] / F_IN;
    const int E = in_sizes[5] / 2;
    const int* src = ei;
    const int* dst = ei + E;

    char* ws = (char*)d_ws;
    size_t off = 0;
    int*   hist     = (int*)(ws + off);   off += align_up((size_t)n * 4, 256);      // reused as cursor
    int*   rowstart = (int*)(ws + off);   off += align_up((size_t)(n + 1) * 4, 256);
    int*   bsum     = (int*)(ws + off);   off += align_up((size_t)512 * 4, 256);
    int*   csrc     = (int*)(ws + off);   off += align_up((size_t)E * 4, 256);
    float* dinv     = (float*)(ws + off); off += align_up((size_t)n * 4, 256);
    float* h0       = (float*)(ws + off); off += align_up((size_t)n * HID * 4, 256);
    float* h2       = (float*)(ws + off); off += align_up((size_t)n * 8 * 4, 256);
    unsigned short* Wt = (unsigned short*)(ws + off); off += align_up((size_t)HID * 512 * 2, 256);
    float* out      = (float*)d_out;

    const int nb = (n + 255) / 256;

    hipMemsetAsync(hist, 0, (size_t)n * 4, stream);
    hist_kernel<<<(E + 255) / 256, 256, 0, stream>>>(dst, hist, E);
    dinv_kernel<<<nb, 256, 0, stream>>>(hist, dinv, n);
    scan1_kernel<<<nb, 256, 0, stream>>>(hist, rowstart, bsum, n);
    scan2_kernel<<<1, 512, 0, stream>>>(bsum, nb);
    scan3_kernel<<<nb, 256, 0, stream>>>(rowstart, bsum, hist /*cursor*/, n, E);
    scatter_kernel<<<(E + 255) / 256, 256, 0, stream>>>(src, dst, hist /*cursor*/, csrc, E);

    wt_kernel<<<(HID * 512 + 255) / 256, 256, 0, stream>>>(W1, Wt);
    gemm1_mfma_kernel<<<(n + 127) / 128, 256, 0, stream>>>(x, Wt, h0, n);

    agg1_gemm2_kernel<<<(n + 3) / 4, 256, 0, stream>>>(h0, dinv, rowstart, csrc, b1, W2, h2, n);

    agg2_kernel<<<((size_t)n * 8 + 255) / 256, 256, 0, stream>>>(h2, dinv, rowstart, csrc, b2, out, n);
}

// Round 6
// 453.458 us; speedup vs baseline: 2.1413x; 1.1112x over previous
//
#include <hip/hip_runtime.h>
#include <cstdint>

#define F_IN 500
#define HID  64
#define NCLS 7

typedef __attribute__((ext_vector_type(8))) short v8s;
typedef __attribute__((ext_vector_type(4))) short v4s;
typedef __attribute__((ext_vector_type(4))) float v4f;

union S8 { v8s v; v4s h[2]; };

static inline size_t align_up(size_t v, size_t a) { return (v + a - 1) & ~(a - 1); }

__device__ inline unsigned short f2bf(float f) {
    unsigned int u = __float_as_uint(f);
    u += 0x7FFF + ((u >> 16) & 1);       // round-to-nearest-even
    return (unsigned short)(u >> 16);
}
__device__ inline float bf2f(unsigned short u) {
    return __uint_as_float(((unsigned int)u) << 16);
}

// ---------- degree histogram (int) ----------
__global__ void hist_kernel(const int* __restrict__ dst, int* __restrict__ hist, int E) {
    int i = blockIdx.x * blockDim.x + threadIdx.x;
    if (i < E) atomicAdd(&hist[dst[i]], 1);
}

// ---------- scan1 + dinv fused ----------
__global__ __launch_bounds__(256) void scan1_kernel(const int* __restrict__ hist,
                                                    int* __restrict__ rowstart,
                                                    int* __restrict__ bsum,
                                                    float* __restrict__ dinv, int n) {
    __shared__ int sdat[256];
    int tid = threadIdx.x;
    int i = blockIdx.x * 256 + tid;
    int v = (i < n) ? hist[i] : 0;
    if (i < n) dinv[i] = rsqrtf((float)v + 1.0f);
    sdat[tid] = v;
    __syncthreads();
    for (int off = 1; off < 256; off <<= 1) {
        int t = (tid >= off) ? sdat[tid - off] : 0;
        __syncthreads();
        sdat[tid] += t;
        __syncthreads();
    }
    int incl = sdat[tid];
    if (i < n) rowstart[i] = incl - v;           // in-block exclusive
    if (tid == 255) bsum[blockIdx.x] = incl;     // block total
}

__global__ __launch_bounds__(512) void scan2_kernel(int* __restrict__ bsum, int nb) {
    __shared__ int sdat[512];
    int tid = threadIdx.x;
    int v = (tid < nb) ? bsum[tid] : 0;
    sdat[tid] = v;
    __syncthreads();
    for (int off = 1; off < 512; off <<= 1) {
        int t = (tid >= off) ? sdat[tid - off] : 0;
        __syncthreads();
        sdat[tid] += t;
        __syncthreads();
    }
    bsum[tid] = sdat[tid] - v;                   // exclusive block offsets
}

__global__ void scan3_kernel(int* __restrict__ rowstart, const int* __restrict__ bsum,
                             int* __restrict__ cursor, int n, int E) {
    int i = blockIdx.x * blockDim.x + threadIdx.x;
    if (i < n) {
        int val = rowstart[i] + bsum[i >> 8];
        rowstart[i] = val;
        cursor[i] = val;
    }
    if (i == 0) rowstart[n] = E;
}

// ---------- scatter edges into CSR (grouped by dst) ----------
__global__ void scatter_kernel(const int* __restrict__ src, const int* __restrict__ dst,
                               int* __restrict__ cursor, int* __restrict__ csrc, int E) {
    int e = blockIdx.x * blockDim.x + threadIdx.x;
    if (e < E) {
        int d = dst[e];
        int pos = atomicAdd(&cursor[d], 1);
        csrc[pos] = src[e];
    }
}

// ---------- W1 -> bf16 transposed+padded  Wt[64][512] ----------
__global__ void wt_kernel(const float* __restrict__ W1, unsigned short* __restrict__ Wt) {
    int id = blockIdx.x * 256 + threadIdx.x;   // 64*512
    if (id >= HID * 512) return;
    int c = id >> 9;
    int k = id & 511;
    Wt[(size_t)c * 512 + k] = (k < F_IN) ? f2bf(W1[(size_t)k * HID + c]) : (unsigned short)0;
}

// ---------- GEMM1 via bf16 MFMA: h0s(bf16) = (x @ W1) * dinv[row] ----------
__global__ __launch_bounds__(256) void gemm1_mfma_kernel(
    const float* __restrict__ x, const unsigned short* __restrict__ Wt,
    const float* __restrict__ dinv,
    unsigned short* __restrict__ h0s, int n)
{
    __shared__ unsigned short Al[128][36];
    __shared__ unsigned short Bl[64][36];

    const int tid  = threadIdx.x;
    const int lane = tid & 63;
    const int wave = tid >> 6;
    const int row0 = blockIdx.x * 128;
    const int l15  = lane & 15;
    const int kq   = (lane >> 4) * 4;

    v4f acc[2][4];
    #pragma unroll
    for (int rb = 0; rb < 2; ++rb)
        #pragma unroll
        for (int cb = 0; cb < 4; ++cb) acc[rb][cb] = (v4f)(0.0f);

    const int a_c4 = tid & 7;     // float4 index along k within chunk
    const int a_r  = tid >> 3;    // row 0..31 (+32*i)
    const int b_c  = tid >> 2;    // col 0..63
    const int b_k8 = (tid & 3) * 8;

    for (int ks = 0; ks < 16; ++ks) {
        const int kbase = ks * 32;
        __syncthreads();
        #pragma unroll
        for (int i = 0; i < 4; ++i) {
            const int r = a_r + 32 * i;
            int row = row0 + r;
            row = (row < n) ? row : (n - 1);
            v4s o;
            if (kbase + a_c4 * 4 < F_IN) {
                float4 v = *reinterpret_cast<const float4*>(
                    x + (size_t)row * F_IN + kbase + a_c4 * 4);
                o.x = (short)f2bf(v.x); o.y = (short)f2bf(v.y);
                o.z = (short)f2bf(v.z); o.w = (short)f2bf(v.w);
            } else {
                o = (v4s)(short)0;
            }
            *reinterpret_cast<v4s*>(&Al[r][a_c4 * 4]) = o;
        }
        {
            const unsigned short* p = Wt + (size_t)b_c * 512 + kbase + b_k8;
            v4s lo = *reinterpret_cast<const v4s*>(p);
            v4s hi = *reinterpret_cast<const v4s*>(p + 4);
            *reinterpret_cast<v4s*>(&Bl[b_c][b_k8])     = lo;
            *reinterpret_cast<v4s*>(&Bl[b_c][b_k8 + 4]) = hi;
        }
        __syncthreads();

        S8 af[2], bq[4];
        #pragma unroll
        for (int rb = 0; rb < 2; ++rb) {
            const int row = wave * 32 + rb * 16 + l15;
            af[rb].h[0] = *reinterpret_cast<const v4s*>(&Al[row][kq]);
            af[rb].h[1] = *reinterpret_cast<const v4s*>(&Al[row][kq + 16]);
        }
        #pragma unroll
        for (int cb = 0; cb < 4; ++cb) {
            const int col = cb * 16 + l15;
            bq[cb].h[0] = *reinterpret_cast<const v4s*>(&Bl[col][kq]);
            bq[cb].h[1] = *reinterpret_cast<const v4s*>(&Bl[col][kq + 16]);
        }
        #pragma unroll
        for (int rb = 0; rb < 2; ++rb)
            #pragma unroll
            for (int cb = 0; cb < 4; ++cb)
                acc[rb][cb] = __builtin_amdgcn_mfma_f32_16x16x32_bf16(
                    af[rb].v, bq[cb].v, acc[rb][cb], 0, 0, 0);
    }

    // store C scaled by dinv[row], bf16: col = cb*16+l15, row = (lane>>4)*4+j
    #pragma unroll
    for (int rb = 0; rb < 2; ++rb) {
        #pragma unroll
        for (int j = 0; j < 4; ++j) {
            int row = row0 + wave * 32 + rb * 16 + (lane >> 4) * 4 + j;
            if (row < n) {
                float di = dinv[row];
                #pragma unroll
                for (int cb = 0; cb < 4; ++cb)
                    h0s[(size_t)row * HID + cb * 16 + l15] = f2bf(acc[rb][cb][j] * di);
            }
        }
    }
}

// ---------- fused layer-1 aggregation + GEMM2: wave per node, unroll-4 gather ----------
// acc = sum_{s in N(d)} h0s[s][lane] + h0s[d][lane]; h1 = dd*acc
// h2s[d][c'] = dd * sum_c relu(h1[c] + b1[c]) * W2[c][c']
__global__ __launch_bounds__(256) void agg1_gemm2_kernel(
    const unsigned short* __restrict__ h0s, const float* __restrict__ dinv,
    const int* __restrict__ rowstart, const int* __restrict__ csrc,
    const float* __restrict__ b1, const float* __restrict__ W2,
    float* __restrict__ h2s, int n)
{
    __shared__ float W2s[HID][9];
    __shared__ float b1s[HID];
    for (int i = threadIdx.x; i < HID * 8; i += 256) {
        int k = i >> 3, c = i & 7;
        W2s[k][c] = (c < NCLS) ? W2[k * NCLS + c] : 0.f;
    }
    if (threadIdx.x < HID) b1s[threadIdx.x] = b1[threadIdx.x];
    __syncthreads();

    const int lane = threadIdx.x & 63;
    const int wave = threadIdx.x >> 6;
    const int d = blockIdx.x * 4 + wave;
    if (d >= n) return;

    const int js = rowstart[d];
    const int je = rowstart[d + 1];
    float acc = 0.f;
    int j = js;
    for (; j + 4 <= je; j += 4) {
        int s0 = csrc[j + 0];
        int s1 = csrc[j + 1];
        int s2 = csrc[j + 2];
        int s3 = csrc[j + 3];
        float v0 = bf2f(h0s[(size_t)s0 * HID + lane]);
        float v1 = bf2f(h0s[(size_t)s1 * HID + lane]);
        float v2 = bf2f(h0s[(size_t)s2 * HID + lane]);
        float v3 = bf2f(h0s[(size_t)s3 * HID + lane]);
        acc += (v0 + v1) + (v2 + v3);
    }
    for (; j < je; ++j)
        acc += bf2f(h0s[(size_t)csrc[j] * HID + lane]);
    acc += bf2f(h0s[(size_t)d * HID + lane]);   // self loop (already dinv[d]-scaled)

    const float dd = dinv[d];
    float p = fmaxf(acc * dd + b1s[lane], 0.f);

    float t0 = p * W2s[lane][0];
    float t1 = p * W2s[lane][1];
    float t2 = p * W2s[lane][2];
    float t3 = p * W2s[lane][3];
    float t4 = p * W2s[lane][4];
    float t5 = p * W2s[lane][5];
    float t6 = p * W2s[lane][6];
    #pragma unroll
    for (int off = 32; off > 0; off >>= 1) {
        t0 += __shfl_xor(t0, off);
        t1 += __shfl_xor(t1, off);
        t2 += __shfl_xor(t2, off);
        t3 += __shfl_xor(t3, off);
        t4 += __shfl_xor(t4, off);
        t5 += __shfl_xor(t5, off);
        t6 += __shfl_xor(t6, off);
    }
    float sel = t0;
    sel = (lane == 1) ? t1 : sel;
    sel = (lane == 2) ? t2 : sel;
    sel = (lane == 3) ? t3 : sel;
    sel = (lane == 4) ? t4 : sel;
    sel = (lane == 5) ? t5 : sel;
    sel = (lane == 6) ? t6 : sel;
    if (lane < NCLS) h2s[(size_t)d * 8 + lane] = sel * dd;   // pre-scaled for layer 2
}

// ---------- layer-2 aggregation: 8 lanes per node, unroll-4 gather ----------
__global__ void agg2_kernel(const float* __restrict__ h2s, const float* __restrict__ dinv,
                            const int* __restrict__ rowstart, const int* __restrict__ csrc,
                            const float* __restrict__ b2, float* __restrict__ out, int n)
{
    int idx = blockIdx.x * blockDim.x + threadIdx.x;
    int d = idx >> 3;
    int c = idx & 7;
    if (d >= n) return;

    const int js = rowstart[d];
    const int je = rowstart[d + 1];
    float acc = 0.f;
    int j = js;
    for (; j + 4 <= je; j += 4) {
        int s0 = csrc[j + 0];
        int s1 = csrc[j + 1];
        int s2 = csrc[j + 2];
        int s3 = csrc[j + 3];
        float v0 = h2s[(size_t)s0 * 8 + c];
        float v1 = h2s[(size_t)s1 * 8 + c];
        float v2 = h2s[(size_t)s2 * 8 + c];
        float v3 = h2s[(size_t)s3 * 8 + c];
        acc += (v0 + v1) + (v2 + v3);
    }
    for (; j < je; ++j)
        acc += h2s[(size_t)csrc[j] * 8 + c];
    acc += h2s[(size_t)d * 8 + c];              // self loop (already dinv[d]-scaled)

    if (c < NCLS)
        out[(size_t)d * NCLS + c] = fmaf(acc, dinv[d], b2[c]);
}

extern "C" void kernel_launch(void* const* d_in, const int* in_sizes, int n_in,
                              void* d_out, int out_size, void* d_ws, size_t ws_size,
                              hipStream_t stream)
{
    const float* x  = (const float*)d_in[0];
    const float* W1 = (const float*)d_in[1];
    const float* b1 = (const float*)d_in[2];
    const float* W2 = (const float*)d_in[3];
    const float* b2 = (const float*)d_in[4];
    const int*   ei = (const int*)d_in[5];

    const int n = in_sizes[0] / F_IN;
    const int E = in_sizes[5] / 2;
    const int* src = ei;
    const int* dst = ei + E;

    char* ws = (char*)d_ws;
    size_t off = 0;
    int*   hist     = (int*)(ws + off);   off += align_up((size_t)n * 4, 256);      // reused as cursor
    int*   rowstart = (int*)(ws + off);   off += align_up((size_t)(n + 1) * 4, 256);
    int*   bsum     = (int*)(ws + off);   off += align_up((size_t)512 * 4, 256);
    int*   csrc     = (int*)(ws + off);   off += align_up((size_t)E * 4, 256);
    float* dinv     = (float*)(ws + off); off += align_up((size_t)n * 4, 256);
    unsigned short* h0s = (unsigned short*)(ws + off); off += align_up((size_t)n * HID * 2, 256);
    float* h2s      = (float*)(ws + off); off += align_up((size_t)n * 8 * 4, 256);
    unsigned short* Wt = (unsigned short*)(ws + off); off += align_up((size_t)HID * 512 * 2, 256);
    float* out      = (float*)d_out;

    const int nb = (n + 255) / 256;

    hipMemsetAsync(hist, 0, (size_t)n * 4, stream);
    hist_kernel<<<(E + 255) / 256, 256, 0, stream>>>(dst, hist, E);
    scan1_kernel<<<nb, 256, 0, stream>>>(hist, rowstart, bsum, dinv, n);
    scan2_kernel<<<1, 512, 0, stream>>>(bsum, nb);
    scan3_kernel<<<nb, 256, 0, stream>>>(rowstart, bsum, hist /*cursor*/, n, E);
    scatter_kernel<<<(E + 255) / 256, 256, 0, stream>>>(src, dst, hist /*cursor*/, csrc, E);

    wt_kernel<<<(HID * 512 + 255) / 256, 256, 0, stream>>>(W1, Wt);
    gemm1_mfma_kernel<<<(n + 127) / 128, 256, 0, stream>>>(x, Wt, dinv, h0s, n);

    agg1_gemm2_kernel<<<(n + 3) / 4, 256, 0, stream>>>(h0s, dinv, rowstart, csrc, b1, W2, h2s, n);

    agg2_kernel<<<((size_t)n * 8 + 255) / 256, 256, 0, stream>>>(h2s, dinv, rowstart, csrc, b2, out, n);
}